// Round 1
// baseline (2416.541 us; speedup 1.0000x reference)
//
#include <hip/hip_runtime.h>

#define HD 128

// ---------------- spline second-derivative solve (natural cubic, K=5) ----------
__global__ void spline_solve(const float* __restrict__ knots,
                             const float* __restrict__ vals,
                             float* __restrict__ M) {
    int f = threadIdx.x;  // 128 features
    float kn[5], v[5];
#pragma unroll
    for (int i = 0; i < 5; ++i) { kn[i] = knots[i]; v[i] = vals[f * 5 + i]; }
    float h[4], sl[4];
#pragma unroll
    for (int i = 0; i < 4; ++i) { h[i] = kn[i + 1] - kn[i]; sl[i] = (v[i + 1] - v[i]) / h[i]; }
    float r0 = 6.f * (sl[1] - sl[0]);
    float r1 = 6.f * (sl[2] - sl[1]);
    float r2 = 6.f * (sl[3] - sl[2]);
    float d0 = 2.f * (h[0] + h[1]), d1 = 2.f * (h[1] + h[2]), d2 = 2.f * (h[2] + h[3]);
    float e0 = h[1], e1 = h[2];
    // Thomas
    float w1 = e0 / d0;  float d1p = d1 - w1 * e0;  float r1p = r1 - w1 * r0;
    float w2 = e1 / d1p; float d2p = d2 - w2 * e1;  float r2p = r2 - w2 * r1p;
    float x2 = r2p / d2p;
    float x1 = (r1p - e1 * x2) / d1p;
    float x0 = (r0 - e0 * x1) / d0;
    M[f * 5 + 0] = 0.f; M[f * 5 + 1] = x0; M[f * 5 + 2] = x1; M[f * 5 + 3] = x2; M[f * 5 + 4] = 0.f;
}

// ---------------- 128x128 weight transpose (for X @ W.T forms) -----------------
__global__ void transpose128(const float* __restrict__ in, float* __restrict__ out) {
    int k = blockIdx.x, h2 = threadIdx.x;
    out[k * HD + h2] = in[h2 * HD + k];
}

// ---------------- GEMM: C(n x 128) = A(n x 128) @ W(128 x 128, k-major) --------
__global__ __launch_bounds__(256) void gemm128(const float* __restrict__ A,
                                               const float* __restrict__ W,
                                               const float* __restrict__ bias,
                                               float* __restrict__ C,
                                               int n, int relu) {
    __shared__ float As[32][132];  // pad to 132 floats: 16B-aligned rows, bank-spread
    const int t = threadIdx.x;
    const int row0 = blockIdx.x * 32;
    // stage A tile: 32 rows x 128 cols = 1024 float4
    for (int i = t; i < 1024; i += 256) {
        int r = i >> 5;
        int c4 = (i & 31) << 2;
        int row = row0 + r;
        float4 v = make_float4(0.f, 0.f, 0.f, 0.f);
        if (row < n) v = *(const float4*)&A[(long)row * HD + c4];
        As[r][c4 + 0] = v.x; As[r][c4 + 1] = v.y; As[r][c4 + 2] = v.z; As[r][c4 + 3] = v.w;
    }
    __syncthreads();
    const int cg = (t & 31) << 2;  // column base (0..124)
    const int rg = (t >> 5) << 2;  // row base within tile (0..28)
    float acc[4][4] = {{0.f}};
    for (int k4 = 0; k4 < HD; k4 += 4) {
        float a[4][4];  // a[i][kk] = As[rg+i][k4+kk]
        float w[4][4];  // w[kk][j] = W[(k4+kk)*128 + cg + j]
#pragma unroll
        for (int i = 0; i < 4; ++i)
            *(float4*)&a[i][0] = *(const float4*)&As[rg + i][k4];
#pragma unroll
        for (int kk = 0; kk < 4; ++kk)
            *(float4*)&w[kk][0] = *(const float4*)&W[(k4 + kk) * HD + cg];
#pragma unroll
        for (int kk = 0; kk < 4; ++kk)
#pragma unroll
            for (int i = 0; i < 4; ++i)
#pragma unroll
                for (int j = 0; j < 4; ++j)
                    acc[i][j] += a[i][kk] * w[kk][j];
    }
    float bv[4] = {0.f, 0.f, 0.f, 0.f};
    if (bias) *(float4*)&bv[0] = *(const float4*)&bias[cg];
#pragma unroll
    for (int i = 0; i < 4; ++i) {
        int row = row0 + rg + i;
        if (row < n) {
            float4 o;
            float ox = acc[i][0] + bv[0];
            float oy = acc[i][1] + bv[1];
            float oz = acc[i][2] + bv[2];
            float ow = acc[i][3] + bv[3];
            if (relu) {
                ox = fmaxf(ox, 0.f); oy = fmaxf(oy, 0.f);
                oz = fmaxf(oz, 0.f); ow = fmaxf(ow, 0.f);
            }
            o.x = ox; o.y = oy; o.z = oz; o.w = ow;
            *(float4*)&C[(long)row * HD + cg] = o;
        }
    }
}

// ---------------- edge scatter: out[dst[e]][f] += T[src[e]][f] -----------------
__global__ __launch_bounds__(256) void scatter_add(const float* __restrict__ T,
                                                   const int* __restrict__ dst,
                                                   const int* __restrict__ src,
                                                   float* __restrict__ out,
                                                   int nE) {
    long idx = (long)blockIdx.x * blockDim.x + threadIdx.x;
    int e = (int)(idx >> 7);
    int f = (int)(idx & 127);
    if (e < nE) {
        int s = src[e];
        int d = dst[e];
        float v = T[(long)s * HD + f];
        atomicAdd(&out[(long)d * HD + f], v);
    }
}

// ---------------- fused KAN affine + cubic spline + fc dot ---------------------
__global__ __launch_bounds__(64) void kan_tail(const float* __restrict__ kl,
                                               const float* __restrict__ alpha,
                                               const float* __restrict__ beta,
                                               const float* __restrict__ knots,
                                               const float* __restrict__ vals,
                                               const float* __restrict__ M,
                                               const float* __restrict__ fcw,
                                               const float* __restrict__ fcb,
                                               float* __restrict__ out, int n) {
    int nid = blockIdx.x;
    if (nid >= n) return;
    int lane = threadIdx.x;
    float kn[5];
#pragma unroll
    for (int i = 0; i < 5; ++i) kn[i] = knots[i];
    float sum = 0.f;
#pragma unroll
    for (int ff = 0; ff < 2; ++ff) {
        int f = lane + 64 * ff;
        float xv = alpha[f] * kl[(long)nid * HD + f] + beta[f];
        // searchsorted(knots, x, side="right") - 1, clipped to [0, 3]
        int j = -1;
#pragma unroll
        for (int i = 0; i < 5; ++i) j += (xv >= kn[i]) ? 1 : 0;
        j = max(0, min(3, j));
        float t0 = kn[j], t1 = kn[j + 1];
        float hj = t1 - t0;
        float y0 = vals[f * 5 + j], y1 = vals[f * 5 + j + 1];
        float M0 = M[f * 5 + j], M1 = M[f * 5 + j + 1];
        float a = t1 - xv, b = xv - t0;
        float inv6h = 1.f / (6.f * hj);
        float s = M0 * a * a * a * inv6h + M1 * b * b * b * inv6h
                + (y0 / hj - M0 * hj / 6.f) * a + (y1 / hj - M1 * hj / 6.f) * b;
        sum += s * fcw[f];
    }
#pragma unroll
    for (int o = 32; o; o >>= 1) sum += __shfl_down(sum, o);
    if (lane == 0) out[nid] = sum + fcb[0];
}

extern "C" void kernel_launch(void* const* d_in, const int* in_sizes, int n_in,
                              void* d_out, int out_size, void* d_ws, size_t ws_size,
                              hipStream_t stream) {
    const float* x       = (const float*)d_in[0];
    const int*   eA[3]   = {(const int*)d_in[1], (const int*)d_in[2], (const int*)d_in[3]};
    const float* W1      = (const float*)d_in[4];   // (3,128,128) k-major per relation
    const float* lin1_w  = (const float*)d_in[5];
    const float* lin1_b  = (const float*)d_in[6];
    const float* W2      = (const float*)d_in[7];
    const float* lin2_w  = (const float*)d_in[8];
    const float* lin2_b  = (const float*)d_in[9];
    const float* kan_w   = (const float*)d_in[10];
    const float* kan_b   = (const float*)d_in[11];
    const float* alpha   = (const float*)d_in[12];
    const float* beta    = (const float*)d_in[13];
    const float* knots   = (const float*)d_in[14];
    const float* spline_vals = (const float*)d_in[15];
    const float* fc_w    = (const float*)d_in[16];
    const float* fc_b    = (const float*)d_in[17];

    const int N = in_sizes[0] / HD;
    const int E = in_sizes[1] / 2;

    // workspace layout (floats)
    float* wsf = (float*)d_ws;
    float* M    = wsf;                 // 640
    float* Wt1  = wsf + 1024;          // 16384
    float* Wt2  = Wt1 + 16384;
    float* WtK  = Wt2 + 16384;
    float* B0   = wsf + 65536;                  // T scratch / h2
    float* B1   = B0 + (long)N * HD;            // agg / kanlin
    float* B2   = B1 + (long)N * HD;            // h1
    const size_t bufBytes = (size_t)N * HD * sizeof(float);

    const int gemmGrid = (N + 31) / 32;
    const int scatGrid = (int)(((long)E * HD + 255) / 256);

    // small precomputes
    spline_solve<<<1, 128, 0, stream>>>(knots, spline_vals, M);
    transpose128<<<128, 128, 0, stream>>>(lin1_w, Wt1);
    transpose128<<<128, 128, 0, stream>>>(lin2_w, Wt2);
    transpose128<<<128, 128, 0, stream>>>(kan_w, WtK);

    // ---- layer 1 ----
    hipMemsetAsync(B1, 0, bufBytes, stream);
    for (int r = 0; r < 3; ++r) {
        gemm128<<<gemmGrid, 256, 0, stream>>>(x, W1 + (long)r * HD * HD, nullptr, B0, N, 0);
        scatter_add<<<scatGrid, 256, 0, stream>>>(B0, eA[r], eA[r] + E, B1, E);
    }
    gemm128<<<gemmGrid, 256, 0, stream>>>(B1, Wt1, lin1_b, B2, N, 1);  // h1 -> B2

    // ---- layer 2 ----
    hipMemsetAsync(B1, 0, bufBytes, stream);
    for (int r = 0; r < 3; ++r) {
        gemm128<<<gemmGrid, 256, 0, stream>>>(B2, W2 + (long)r * HD * HD, nullptr, B0, N, 0);
        scatter_add<<<scatGrid, 256, 0, stream>>>(B0, eA[r], eA[r] + E, B1, E);
    }
    gemm128<<<gemmGrid, 256, 0, stream>>>(B1, Wt2, lin2_b, B0, N, 1);  // h2 -> B0

    // ---- KAN linear ----
    gemm128<<<gemmGrid, 256, 0, stream>>>(B0, WtK, kan_b, B1, N, 0);   // kanlin -> B1

    // ---- spline + fc ----
    kan_tail<<<N, 64, 0, stream>>>(B1, alpha, beta, knots, spline_vals, M,
                                   fc_w, fc_b, (float*)d_out, N);
}

// Round 2
// 1106.405 us; speedup vs baseline: 2.1841x; 2.1841x over previous
//
#include <hip/hip_runtime.h>

#define HD 128

// ---------------- spline second-derivative solve (natural cubic, K=5) ----------
__global__ void spline_solve(const float* __restrict__ knots,
                             const float* __restrict__ vals,
                             float* __restrict__ M) {
    int f = threadIdx.x;  // 128 features
    float kn[5], v[5];
#pragma unroll
    for (int i = 0; i < 5; ++i) { kn[i] = knots[i]; v[i] = vals[f * 5 + i]; }
    float h[4], sl[4];
#pragma unroll
    for (int i = 0; i < 4; ++i) { h[i] = kn[i + 1] - kn[i]; sl[i] = (v[i + 1] - v[i]) / h[i]; }
    float r0 = 6.f * (sl[1] - sl[0]);
    float r1 = 6.f * (sl[2] - sl[1]);
    float r2 = 6.f * (sl[3] - sl[2]);
    float d0 = 2.f * (h[0] + h[1]), d1 = 2.f * (h[1] + h[2]), d2 = 2.f * (h[2] + h[3]);
    float e0 = h[1], e1 = h[2];
    float w1 = e0 / d0;  float d1p = d1 - w1 * e0;  float r1p = r1 - w1 * r0;
    float w2 = e1 / d1p; float d2p = d2 - w2 * e1;  float r2p = r2 - w2 * r1p;
    float x2 = r2p / d2p;
    float x1 = (r1p - e1 * x2) / d1p;
    float x0 = (r0 - e0 * x1) / d0;
    M[f * 5 + 0] = 0.f; M[f * 5 + 1] = x0; M[f * 5 + 2] = x1; M[f * 5 + 3] = x2; M[f * 5 + 4] = 0.f;
}

// ---------------- 128x128 weight transpose (for X @ W.T forms) -----------------
__global__ void transpose128(const float* __restrict__ in, float* __restrict__ out) {
    int k = blockIdx.x, h2 = threadIdx.x;
    out[k * HD + h2] = in[h2 * HD + k];
}

// ---------------- GEMM: C(n x 128) = A(n x 128) @ W(128 x 128, k-major) --------
__global__ __launch_bounds__(256) void gemm128(const float* __restrict__ A,
                                               const float* __restrict__ W,
                                               const float* __restrict__ bias,
                                               float* __restrict__ C,
                                               int n, int relu) {
    __shared__ float As[32][132];
    const int t = threadIdx.x;
    const int row0 = blockIdx.x * 32;
    for (int i = t; i < 1024; i += 256) {
        int r = i >> 5;
        int c4 = (i & 31) << 2;
        int row = row0 + r;
        float4 v = make_float4(0.f, 0.f, 0.f, 0.f);
        if (row < n) v = *(const float4*)&A[(long)row * HD + c4];
        As[r][c4 + 0] = v.x; As[r][c4 + 1] = v.y; As[r][c4 + 2] = v.z; As[r][c4 + 3] = v.w;
    }
    __syncthreads();
    const int cg = (t & 31) << 2;
    const int rg = (t >> 5) << 2;
    float acc[4][4] = {{0.f}};
    for (int k4 = 0; k4 < HD; k4 += 4) {
        float a[4][4];
        float w[4][4];
#pragma unroll
        for (int i = 0; i < 4; ++i)
            *(float4*)&a[i][0] = *(const float4*)&As[rg + i][k4];
#pragma unroll
        for (int kk = 0; kk < 4; ++kk)
            *(float4*)&w[kk][0] = *(const float4*)&W[(k4 + kk) * HD + cg];
#pragma unroll
        for (int kk = 0; kk < 4; ++kk)
#pragma unroll
            for (int i = 0; i < 4; ++i)
#pragma unroll
                for (int j = 0; j < 4; ++j)
                    acc[i][j] += a[i][kk] * w[kk][j];
    }
    float bv[4] = {0.f, 0.f, 0.f, 0.f};
    if (bias) *(float4*)&bv[0] = *(const float4*)&bias[cg];
#pragma unroll
    for (int i = 0; i < 4; ++i) {
        int row = row0 + rg + i;
        if (row < n) {
            float4 o;
            float ox = acc[i][0] + bv[0];
            float oy = acc[i][1] + bv[1];
            float oz = acc[i][2] + bv[2];
            float ow = acc[i][3] + bv[3];
            if (relu) {
                ox = fmaxf(ox, 0.f); oy = fmaxf(oy, 0.f);
                oz = fmaxf(oz, 0.f); ow = fmaxf(ow, 0.f);
            }
            o.x = ox; o.y = oy; o.z = oz; o.w = ow;
            *(float4*)&C[(long)row * HD + cg] = o;
        }
    }
}

// ---------------- CSR build ----------------------------------------------------
__global__ void csr_count(const int* __restrict__ dst, int* __restrict__ counts, int nE) {
    int e = blockIdx.x * blockDim.x + threadIdx.x;
    if (e < nE) atomicAdd(&counts[dst[e]], 1);
}

// one block per relation; exclusive scan of counts -> rowptr + cursor copy
__global__ __launch_bounds__(1024) void csr_scan(const int* __restrict__ counts,
                                                 int* __restrict__ rowptr,
                                                 int* __restrict__ cursor,
                                                 int n, int nE) {
    int r = blockIdx.x;
    const int* c = counts + (long)r * n;
    int* rp = rowptr + (long)r * (n + 1);
    int* cur = cursor + (long)r * n;
    __shared__ int sums[1024];
    int t = threadIdx.x;
    int chunk = (n + 1023) / 1024;
    int b0 = t * chunk;
    int b1 = min(b0 + chunk, n);
    int s = 0;
    for (int i = b0; i < b1; ++i) s += c[i];
    sums[t] = s;
    __syncthreads();
    for (int off = 1; off < 1024; off <<= 1) {
        int v = (t >= off) ? sums[t - off] : 0;
        __syncthreads();
        sums[t] += v;
        __syncthreads();
    }
    int excl = sums[t] - s;
    for (int i = b0; i < b1; ++i) {
        rp[i] = excl;
        cur[i] = excl;
        excl += c[i];
    }
    if (t == 1023) rp[n] = nE;
}

__global__ void csr_fill(const int* __restrict__ dst, const int* __restrict__ src,
                         int* __restrict__ cursor, int* __restrict__ srcs, int nE) {
    int e = blockIdx.x * blockDim.x + threadIdx.x;
    if (e < nE) {
        int pos = atomicAdd(&cursor[dst[e]], 1);
        srcs[pos] = src[e];
    }
}

// ---------------- gather-based aggregation: out[d] (+)= sum_e T[srcs[e]] -------
__global__ __launch_bounds__(256) void csr_agg(const float* __restrict__ T,
                                               const int* __restrict__ rowptr,
                                               const int* __restrict__ srcs,
                                               float* __restrict__ out,
                                               int n, int accum) {
    const int g = threadIdx.x >> 5;      // 8 groups per block
    const int lane = threadIdx.x & 31;   // 32 lanes -> float4 each = 128 feats
    const int d = blockIdx.x * 8 + g;
    if (d >= n) return;
    const int beg = rowptr[d], end = rowptr[d + 1];
    float4 a0 = make_float4(0.f, 0.f, 0.f, 0.f);
    float4 a1 = make_float4(0.f, 0.f, 0.f, 0.f);
    int e = beg;
    for (; e + 1 < end; e += 2) {
        int s0 = srcs[e], s1 = srcs[e + 1];
        float4 v0 = *(const float4*)&T[(long)s0 * HD + lane * 4];
        float4 v1 = *(const float4*)&T[(long)s1 * HD + lane * 4];
        a0.x += v0.x; a0.y += v0.y; a0.z += v0.z; a0.w += v0.w;
        a1.x += v1.x; a1.y += v1.y; a1.z += v1.z; a1.w += v1.w;
    }
    if (e < end) {
        int s0 = srcs[e];
        float4 v0 = *(const float4*)&T[(long)s0 * HD + lane * 4];
        a0.x += v0.x; a0.y += v0.y; a0.z += v0.z; a0.w += v0.w;
    }
    a0.x += a1.x; a0.y += a1.y; a0.z += a1.z; a0.w += a1.w;
    float* op = &out[(long)d * HD + lane * 4];
    if (accum) {
        float4 o = *(const float4*)op;
        a0.x += o.x; a0.y += o.y; a0.z += o.z; a0.w += o.w;
    }
    *(float4*)op = a0;
}

// ---------------- fused KAN affine + cubic spline + fc dot ---------------------
__global__ __launch_bounds__(64) void kan_tail(const float* __restrict__ kl,
                                               const float* __restrict__ alpha,
                                               const float* __restrict__ beta,
                                               const float* __restrict__ knots,
                                               const float* __restrict__ vals,
                                               const float* __restrict__ M,
                                               const float* __restrict__ fcw,
                                               const float* __restrict__ fcb,
                                               float* __restrict__ out, int n) {
    int nid = blockIdx.x;
    if (nid >= n) return;
    int lane = threadIdx.x;
    float kn[5];
#pragma unroll
    for (int i = 0; i < 5; ++i) kn[i] = knots[i];
    float sum = 0.f;
#pragma unroll
    for (int ff = 0; ff < 2; ++ff) {
        int f = lane + 64 * ff;
        float xv = alpha[f] * kl[(long)nid * HD + f] + beta[f];
        int j = -1;
#pragma unroll
        for (int i = 0; i < 5; ++i) j += (xv >= kn[i]) ? 1 : 0;
        j = max(0, min(3, j));
        float t0 = kn[j], t1 = kn[j + 1];
        float hj = t1 - t0;
        float y0 = vals[f * 5 + j], y1 = vals[f * 5 + j + 1];
        float M0 = M[f * 5 + j], M1 = M[f * 5 + j + 1];
        float a = t1 - xv, b = xv - t0;
        float inv6h = 1.f / (6.f * hj);
        float s = M0 * a * a * a * inv6h + M1 * b * b * b * inv6h
                + (y0 / hj - M0 * hj / 6.f) * a + (y1 / hj - M1 * hj / 6.f) * b;
        sum += s * fcw[f];
    }
#pragma unroll
    for (int o = 32; o; o >>= 1) sum += __shfl_down(sum, o);
    if (lane == 0) out[nid] = sum + fcb[0];
}

extern "C" void kernel_launch(void* const* d_in, const int* in_sizes, int n_in,
                              void* d_out, int out_size, void* d_ws, size_t ws_size,
                              hipStream_t stream) {
    const float* x       = (const float*)d_in[0];
    const int*   eA[3]   = {(const int*)d_in[1], (const int*)d_in[2], (const int*)d_in[3]};
    const float* W1      = (const float*)d_in[4];
    const float* lin1_w  = (const float*)d_in[5];
    const float* lin1_b  = (const float*)d_in[6];
    const float* W2      = (const float*)d_in[7];
    const float* lin2_w  = (const float*)d_in[8];
    const float* lin2_b  = (const float*)d_in[9];
    const float* kan_w   = (const float*)d_in[10];
    const float* kan_b   = (const float*)d_in[11];
    const float* alpha   = (const float*)d_in[12];
    const float* beta    = (const float*)d_in[13];
    const float* knots   = (const float*)d_in[14];
    const float* spline_vals = (const float*)d_in[15];
    const float* fc_w    = (const float*)d_in[16];
    const float* fc_b    = (const float*)d_in[17];

    const int N = in_sizes[0] / HD;
    const int E = in_sizes[1] / 2;

    // ---- workspace carve (bytes) ----
    char* p = (char*)d_ws;
    float* M      = (float*)p;               p += 4096;
    float* Wt1    = (float*)p;               p += HD * HD * 4;
    float* Wt2    = (float*)p;               p += HD * HD * 4;
    float* WtK    = (float*)p;               p += HD * HD * 4;
    int*   counts = (int*)p;                 p += (size_t)3 * N * 4;
    int*   rowptr = (int*)p;                 p += (size_t)3 * (N + 1) * 4 + 64;
    int*   cursor = (int*)p;                 p += (size_t)3 * N * 4;
    int*   srcs   = (int*)p;                 p += (size_t)3 * E * 4;
    float* B0     = (float*)p;               p += (size_t)N * HD * 4;  // T scratch / h2
    float* B1     = (float*)p;               p += (size_t)N * HD * 4;  // agg / kanlin
    float* B2     = (float*)p;               p += (size_t)N * HD * 4;  // h1

    const int gemmGrid = (N + 31) / 32;
    const int aggGrid  = (N + 7) / 8;
    const int edgeGrid = (E + 255) / 256;

    // small precomputes
    spline_solve<<<1, 128, 0, stream>>>(knots, spline_vals, M);
    transpose128<<<128, 128, 0, stream>>>(lin1_w, Wt1);
    transpose128<<<128, 128, 0, stream>>>(lin2_w, Wt2);
    transpose128<<<128, 128, 0, stream>>>(kan_w, WtK);

    // ---- CSR build (once; reused by both layers) ----
    hipMemsetAsync(counts, 0, (size_t)3 * N * 4, stream);
    for (int r = 0; r < 3; ++r)
        csr_count<<<edgeGrid, 256, 0, stream>>>(eA[r], counts + (long)r * N, E);
    csr_scan<<<3, 1024, 0, stream>>>(counts, rowptr, cursor, N, E);
    for (int r = 0; r < 3; ++r)
        csr_fill<<<edgeGrid, 256, 0, stream>>>(eA[r], eA[r] + E,
                                               cursor + (long)r * N,
                                               srcs + (long)r * E, E);

    // ---- layer 1 ----
    for (int r = 0; r < 3; ++r) {
        gemm128<<<gemmGrid, 256, 0, stream>>>(x, W1 + (long)r * HD * HD, nullptr, B0, N, 0);
        csr_agg<<<aggGrid, 256, 0, stream>>>(B0, rowptr + (long)r * (N + 1),
                                             srcs + (long)r * E, B1, N, r > 0);
    }
    gemm128<<<gemmGrid, 256, 0, stream>>>(B1, Wt1, lin1_b, B2, N, 1);  // h1 -> B2

    // ---- layer 2 ----
    for (int r = 0; r < 3; ++r) {
        gemm128<<<gemmGrid, 256, 0, stream>>>(B2, W2 + (long)r * HD * HD, nullptr, B0, N, 0);
        csr_agg<<<aggGrid, 256, 0, stream>>>(B0, rowptr + (long)r * (N + 1),
                                             srcs + (long)r * E, B1, N, r > 0);
    }
    gemm128<<<gemmGrid, 256, 0, stream>>>(B1, Wt2, lin2_b, B0, N, 1);  // h2 -> B0

    // ---- KAN linear ----
    gemm128<<<gemmGrid, 256, 0, stream>>>(B0, WtK, kan_b, B1, N, 0);   // kanlin -> B1

    // ---- spline + fc ----
    kan_tail<<<N, 64, 0, stream>>>(B1, alpha, beta, knots, spline_vals, M,
                                   fc_w, fc_b, (float*)d_out, N);
}

// Round 3
// 843.945 us; speedup vs baseline: 2.8634x; 1.3110x over previous
//
#include <hip/hip_runtime.h>

#define HD 128

static __device__ __forceinline__ float bf2f(unsigned short u) {
    union { unsigned int i; float f; } c; c.i = ((unsigned int)u) << 16; return c.f;
}
static __device__ __forceinline__ unsigned short f2bf(float f) {
    union { float f; unsigned int i; } c; c.f = f;
    unsigned int lsb = (c.i >> 16) & 1;
    c.i += 0x7fffu + lsb;
    return (unsigned short)(c.i >> 16);
}

// ---------------- spline second-derivative solve (natural cubic, K=5) ----------
__global__ void spline_solve(const float* __restrict__ knots,
                             const float* __restrict__ vals,
                             float* __restrict__ M) {
    int f = threadIdx.x;  // 128 features
    float kn[5], v[5];
#pragma unroll
    for (int i = 0; i < 5; ++i) { kn[i] = knots[i]; v[i] = vals[f * 5 + i]; }
    float h[4], sl[4];
#pragma unroll
    for (int i = 0; i < 4; ++i) { h[i] = kn[i + 1] - kn[i]; sl[i] = (v[i + 1] - v[i]) / h[i]; }
    float r0 = 6.f * (sl[1] - sl[0]);
    float r1 = 6.f * (sl[2] - sl[1]);
    float r2 = 6.f * (sl[3] - sl[2]);
    float d0 = 2.f * (h[0] + h[1]), d1 = 2.f * (h[1] + h[2]), d2 = 2.f * (h[2] + h[3]);
    float e0 = h[1], e1 = h[2];
    float w1 = e0 / d0;  float d1p = d1 - w1 * e0;  float r1p = r1 - w1 * r0;
    float w2 = e1 / d1p; float d2p = d2 - w2 * e1;  float r2p = r2 - w2 * r1p;
    float x2 = r2p / d2p;
    float x1 = (r1p - e1 * x2) / d1p;
    float x0 = (r0 - e0 * x1) / d0;
    M[f * 5 + 0] = 0.f; M[f * 5 + 1] = x0; M[f * 5 + 2] = x1; M[f * 5 + 3] = x2; M[f * 5 + 4] = 0.f;
}

// ---------------- 128x128 weight transpose (for X @ W.T forms) -----------------
__global__ void transpose128(const float* __restrict__ in, float* __restrict__ out) {
    int k = blockIdx.x, h2 = threadIdx.x;
    out[k * HD + h2] = in[h2 * HD + k];
}

// ---------------- GEMM: C(n x 128) = A(n x 128) @ W(128 x 128, k-major) --------
__global__ __launch_bounds__(256) void gemm128(const float* __restrict__ A,
                                               const float* __restrict__ W,
                                               const float* __restrict__ bias,
                                               float* __restrict__ C,
                                               int n, int relu) {
    __shared__ float As[32][132];
    const int t = threadIdx.x;
    const int row0 = blockIdx.x * 32;
    for (int i = t; i < 1024; i += 256) {
        int r = i >> 5;
        int c4 = (i & 31) << 2;
        int row = row0 + r;
        float4 v = make_float4(0.f, 0.f, 0.f, 0.f);
        if (row < n) v = *(const float4*)&A[(long)row * HD + c4];
        As[r][c4 + 0] = v.x; As[r][c4 + 1] = v.y; As[r][c4 + 2] = v.z; As[r][c4 + 3] = v.w;
    }
    __syncthreads();
    const int cg = (t & 31) << 2;
    const int rg = (t >> 5) << 2;
    float acc[4][4] = {{0.f}};
    for (int k4 = 0; k4 < HD; k4 += 4) {
        float a[4][4];
        float w[4][4];
#pragma unroll
        for (int i = 0; i < 4; ++i)
            *(float4*)&a[i][0] = *(const float4*)&As[rg + i][k4];
#pragma unroll
        for (int kk = 0; kk < 4; ++kk)
            *(float4*)&w[kk][0] = *(const float4*)&W[(k4 + kk) * HD + cg];
#pragma unroll
        for (int kk = 0; kk < 4; ++kk)
#pragma unroll
            for (int i = 0; i < 4; ++i)
#pragma unroll
                for (int j = 0; j < 4; ++j)
                    acc[i][j] += a[i][kk] * w[kk][j];
    }
    float bv[4] = {0.f, 0.f, 0.f, 0.f};
    if (bias) *(float4*)&bv[0] = *(const float4*)&bias[cg];
#pragma unroll
    for (int i = 0; i < 4; ++i) {
        int row = row0 + rg + i;
        if (row < n) {
            float4 o;
            float ox = acc[i][0] + bv[0];
            float oy = acc[i][1] + bv[1];
            float oz = acc[i][2] + bv[2];
            float ow = acc[i][3] + bv[3];
            if (relu) {
                ox = fmaxf(ox, 0.f); oy = fmaxf(oy, 0.f);
                oz = fmaxf(oz, 0.f); ow = fmaxf(ow, 0.f);
            }
            o.x = ox; o.y = oy; o.z = oz; o.w = ow;
            *(float4*)&C[(long)row * HD + cg] = o;
        }
    }
}

// ---------------- relation GEMM: T(n x 384, bf16) = A @ W[rel], rel=blockIdx.y --
__global__ __launch_bounds__(256) void gemm128_rel(const float* __restrict__ A,
                                                   const float* __restrict__ Wall,
                                                   unsigned short* __restrict__ T,
                                                   int n) {
    __shared__ float As[32][132];
    const int rel = blockIdx.y;
    const float* W = Wall + (long)rel * HD * HD;
    const int t = threadIdx.x;
    const int row0 = blockIdx.x * 32;
    for (int i = t; i < 1024; i += 256) {
        int r = i >> 5;
        int c4 = (i & 31) << 2;
        int row = row0 + r;
        float4 v = make_float4(0.f, 0.f, 0.f, 0.f);
        if (row < n) v = *(const float4*)&A[(long)row * HD + c4];
        As[r][c4 + 0] = v.x; As[r][c4 + 1] = v.y; As[r][c4 + 2] = v.z; As[r][c4 + 3] = v.w;
    }
    __syncthreads();
    const int cg = (t & 31) << 2;
    const int rg = (t >> 5) << 2;
    float acc[4][4] = {{0.f}};
    for (int k4 = 0; k4 < HD; k4 += 4) {
        float a[4][4];
        float w[4][4];
#pragma unroll
        for (int i = 0; i < 4; ++i)
            *(float4*)&a[i][0] = *(const float4*)&As[rg + i][k4];
#pragma unroll
        for (int kk = 0; kk < 4; ++kk)
            *(float4*)&w[kk][0] = *(const float4*)&W[(k4 + kk) * HD + cg];
#pragma unroll
        for (int kk = 0; kk < 4; ++kk)
#pragma unroll
            for (int i = 0; i < 4; ++i)
#pragma unroll
                for (int j = 0; j < 4; ++j)
                    acc[i][j] += a[i][kk] * w[kk][j];
    }
#pragma unroll
    for (int i = 0; i < 4; ++i) {
        int row = row0 + rg + i;
        if (row < n) {
            ushort4 o;
            o.x = f2bf(acc[i][0]); o.y = f2bf(acc[i][1]);
            o.z = f2bf(acc[i][2]); o.w = f2bf(acc[i][3]);
            *(ushort4*)&T[(long)row * 384 + rel * HD + cg] = o;
        }
    }
}

// ---------------- KAN GEMM fused with spline + fc dot --------------------------
__global__ __launch_bounds__(256) void gemm_kan(const float* __restrict__ A,
                                                const float* __restrict__ W,
                                                const float* __restrict__ bias,
                                                const float* __restrict__ alpha,
                                                const float* __restrict__ beta,
                                                const float* __restrict__ knots,
                                                const float* __restrict__ vals,
                                                const float* __restrict__ M,
                                                const float* __restrict__ fcw,
                                                const float* __restrict__ fcb,
                                                float* __restrict__ out, int n) {
    __shared__ float As[32][132];
    __shared__ float sred[32][33];
    const int t = threadIdx.x;
    const int row0 = blockIdx.x * 32;
    for (int i = t; i < 1024; i += 256) {
        int r = i >> 5;
        int c4 = (i & 31) << 2;
        int row = row0 + r;
        float4 v = make_float4(0.f, 0.f, 0.f, 0.f);
        if (row < n) v = *(const float4*)&A[(long)row * HD + c4];
        As[r][c4 + 0] = v.x; As[r][c4 + 1] = v.y; As[r][c4 + 2] = v.z; As[r][c4 + 3] = v.w;
    }
    __syncthreads();
    const int cg = (t & 31) << 2;
    const int rg = (t >> 5) << 2;
    float acc[4][4] = {{0.f}};
    for (int k4 = 0; k4 < HD; k4 += 4) {
        float a[4][4];
        float w[4][4];
#pragma unroll
        for (int i = 0; i < 4; ++i)
            *(float4*)&a[i][0] = *(const float4*)&As[rg + i][k4];
#pragma unroll
        for (int kk = 0; kk < 4; ++kk)
            *(float4*)&w[kk][0] = *(const float4*)&W[(k4 + kk) * HD + cg];
#pragma unroll
        for (int kk = 0; kk < 4; ++kk)
#pragma unroll
            for (int i = 0; i < 4; ++i)
#pragma unroll
                for (int j = 0; j < 4; ++j)
                    acc[i][j] += a[i][kk] * w[kk][j];
    }
    float kn[5];
#pragma unroll
    for (int i = 0; i < 5; ++i) kn[i] = knots[i];
    float bv[4], al[4], be[4], fw[4];
    *(float4*)bv = *(const float4*)&bias[cg];
    *(float4*)al = *(const float4*)&alpha[cg];
    *(float4*)be = *(const float4*)&beta[cg];
    *(float4*)fw = *(const float4*)&fcw[cg];
    float part[4] = {0.f, 0.f, 0.f, 0.f};
#pragma unroll
    for (int j = 0; j < 4; ++j) {
        int f = cg + j;
#pragma unroll
        for (int i = 0; i < 4; ++i) {
            float xv = al[j] * (acc[i][j] + bv[j]) + be[j];
            int jj = -1;
#pragma unroll
            for (int k = 0; k < 5; ++k) jj += (xv >= kn[k]) ? 1 : 0;
            jj = max(0, min(3, jj));
            float t0 = kn[jj], t1 = kn[jj + 1];
            float hj = t1 - t0;
            float y0 = vals[f * 5 + jj], y1 = vals[f * 5 + jj + 1];
            float M0 = M[f * 5 + jj], M1 = M[f * 5 + jj + 1];
            float a = t1 - xv, b = xv - t0;
            float inv6h = 1.f / (6.f * hj);
            float s = M0 * a * a * a * inv6h + M1 * b * b * b * inv6h
                    + (y0 / hj - M0 * hj / 6.f) * a + (y1 / hj - M1 * hj / 6.f) * b;
            part[i] += s * fw[j];
        }
    }
    const int cg32 = t & 31;
#pragma unroll
    for (int i = 0; i < 4; ++i) sred[rg + i][cg32] = part[i];
    __syncthreads();
    if (t < 32) {
        float s = 0.f;
#pragma unroll
        for (int c = 0; c < 32; ++c) s += sred[t][c];
        int row = row0 + t;
        if (row < n) out[row] = s + fcb[0];
    }
}

// ---------------- CSR build (fused over 3 relations, blockIdx.y = relation) ----
__global__ void csr_count3(const int* __restrict__ e0, const int* __restrict__ e1,
                           const int* __restrict__ e2, int* __restrict__ counts,
                           int E, int N) {
    int r = blockIdx.y;
    const int* dst = (r == 0) ? e0 : ((r == 1) ? e1 : e2);
    int e = blockIdx.x * blockDim.x + threadIdx.x;
    if (e < E) atomicAdd(&counts[(long)r * N + dst[e]], 1);
}

// exclusive scan over flat counts[0..n): phase A (per-block scan + block sums)
__global__ __launch_bounds__(256) void scanA(const int* __restrict__ cnt,
                                             int* __restrict__ S,
                                             int* __restrict__ bsum, int n) {
    __shared__ int ts[256];
    const int t = threadIdx.x;
    const int base = blockIdx.x * 2048 + t * 8;
    int v[8];
    int s = 0;
#pragma unroll
    for (int i = 0; i < 8; ++i) {
        int j = base + i;
        v[i] = (j < n) ? cnt[j] : 0;
        s += v[i];
    }
    ts[t] = s;
    __syncthreads();
    for (int off = 1; off < 256; off <<= 1) {
        int x = (t >= off) ? ts[t - off] : 0;
        __syncthreads();
        ts[t] += x;
        __syncthreads();
    }
    int excl = ts[t] - s;
#pragma unroll
    for (int i = 0; i < 8; ++i) {
        int j = base + i;
        if (j < n) S[j] = excl;
        excl += v[i];
    }
    if (t == 255) bsum[blockIdx.x] = ts[255];
}

// phase C: add block offsets (each block redundantly sums bsum[0..bid)), copy cursor
__global__ __launch_bounds__(256) void scanC(int* __restrict__ S,
                                             int* __restrict__ cursor,
                                             const int* __restrict__ bsum,
                                             int n, int total) {
    __shared__ int red[256];
    const int t = threadIdx.x;
    int acc = 0;
    for (int b = t; b < blockIdx.x; b += 256) acc += bsum[b];
    red[t] = acc;
    __syncthreads();
    for (int o = 128; o; o >>= 1) {
        if (t < o) red[t] += red[t + o];
        __syncthreads();
    }
    const int off = red[0];
    const int base = blockIdx.x * 2048 + t * 8;
#pragma unroll
    for (int i = 0; i < 8; ++i) {
        int j = base + i;
        if (j < n) {
            int val = S[j] + off;
            S[j] = val;
            cursor[j] = val;
        }
    }
    if (blockIdx.x == gridDim.x - 1 && t == 0) S[n] = total;
}

__global__ void csr_fill3(const int* __restrict__ e0, const int* __restrict__ e1,
                          const int* __restrict__ e2, int* __restrict__ cursor,
                          int* __restrict__ srcs, int E, int N) {
    int r = blockIdx.y;
    const int* eb = (r == 0) ? e0 : ((r == 1) ? e1 : e2);
    int e = blockIdx.x * blockDim.x + threadIdx.x;
    if (e < E) {
        int pos = atomicAdd(&cursor[(long)r * N + eb[e]], 1);
        srcs[pos] = eb[E + e];
    }
}

// ---------------- fused 3-relation gather aggregation (bf16 in, f32 out) -------
__global__ __launch_bounds__(256) void csr_agg3(const unsigned short* __restrict__ T,
                                                const int* __restrict__ S,
                                                const int* __restrict__ srcs,
                                                float* __restrict__ out, int N) {
    const int g = threadIdx.x >> 5;
    const int lane = threadIdx.x & 31;
    const int d = blockIdx.x * 8 + g;
    if (d >= N) return;
    float a0[4] = {0.f, 0.f, 0.f, 0.f};
    float a1[4] = {0.f, 0.f, 0.f, 0.f};
#pragma unroll
    for (int r = 0; r < 3; ++r) {
        const int beg = S[(long)r * N + d];
        const int end = S[(long)r * N + d + 1];
        const unsigned short* Tb = T + r * HD + lane * 4;
        int e = beg;
        for (; e + 1 < end; e += 2) {
            ushort4 u0 = *(const ushort4*)&Tb[(long)srcs[e] * 384];
            ushort4 u1 = *(const ushort4*)&Tb[(long)srcs[e + 1] * 384];
            a0[0] += bf2f(u0.x); a0[1] += bf2f(u0.y); a0[2] += bf2f(u0.z); a0[3] += bf2f(u0.w);
            a1[0] += bf2f(u1.x); a1[1] += bf2f(u1.y); a1[2] += bf2f(u1.z); a1[3] += bf2f(u1.w);
        }
        if (e < end) {
            ushort4 u0 = *(const ushort4*)&Tb[(long)srcs[e] * 384];
            a0[0] += bf2f(u0.x); a0[1] += bf2f(u0.y); a0[2] += bf2f(u0.z); a0[3] += bf2f(u0.w);
        }
    }
    float4 o;
    o.x = a0[0] + a1[0]; o.y = a0[1] + a1[1];
    o.z = a0[2] + a1[2]; o.w = a0[3] + a1[3];
    *(float4*)&out[(long)d * HD + lane * 4] = o;
}

extern "C" void kernel_launch(void* const* d_in, const int* in_sizes, int n_in,
                              void* d_out, int out_size, void* d_ws, size_t ws_size,
                              hipStream_t stream) {
    const float* x       = (const float*)d_in[0];
    const int*   eA[3]   = {(const int*)d_in[1], (const int*)d_in[2], (const int*)d_in[3]};
    const float* W1      = (const float*)d_in[4];
    const float* lin1_w  = (const float*)d_in[5];
    const float* lin1_b  = (const float*)d_in[6];
    const float* W2      = (const float*)d_in[7];
    const float* lin2_w  = (const float*)d_in[8];
    const float* lin2_b  = (const float*)d_in[9];
    const float* kan_w   = (const float*)d_in[10];
    const float* kan_b   = (const float*)d_in[11];
    const float* alpha   = (const float*)d_in[12];
    const float* beta    = (const float*)d_in[13];
    const float* knots   = (const float*)d_in[14];
    const float* spline_vals = (const float*)d_in[15];
    const float* fc_w    = (const float*)d_in[16];
    const float* fc_b    = (const float*)d_in[17];

    const int N = in_sizes[0] / HD;
    const int E = in_sizes[1] / 2;
    const int n3 = 3 * N;

    // ---- workspace carve (bytes) ----
    char* p = (char*)d_ws;
    float* M      = (float*)p;            p += 4096;
    float* Wt1    = (float*)p;            p += HD * HD * 4;
    float* Wt2    = (float*)p;            p += HD * HD * 4;
    float* WtK    = (float*)p;            p += HD * HD * 4;
    int*   counts = (int*)p;              p += (size_t)n3 * 4 + 256;
    int*   S      = (int*)p;              p += (size_t)(n3 + 1) * 4 + 256;
    int*   cursor = (int*)p;              p += (size_t)n3 * 4 + 256;
    int*   bsum   = (int*)p;              p += 4096;
    int*   srcs   = (int*)p;              p += (size_t)3 * E * 4;
    unsigned short* T = (unsigned short*)p; p += (size_t)N * 384 * 2;
    float* B1     = (float*)p;            p += (size_t)N * HD * 4;  // agg out
    float* B2     = (float*)p;            p += (size_t)N * HD * 4;  // h1 / h2

    const int gemmGrid = (N + 31) / 32;
    const int aggGrid  = (N + 7) / 8;
    const int edgeGrid = (E + 255) / 256;
    const int scanGrid = (n3 + 2047) / 2048;

    // small precomputes
    spline_solve<<<1, 128, 0, stream>>>(knots, spline_vals, M);
    transpose128<<<128, 128, 0, stream>>>(lin1_w, Wt1);
    transpose128<<<128, 128, 0, stream>>>(lin2_w, Wt2);
    transpose128<<<128, 128, 0, stream>>>(kan_w, WtK);

    // ---- CSR build (once; reused by both layers) ----
    hipMemsetAsync(counts, 0, (size_t)n3 * 4, stream);
    csr_count3<<<dim3(edgeGrid, 3), 256, 0, stream>>>(eA[0], eA[1], eA[2], counts, E, N);
    scanA<<<scanGrid, 256, 0, stream>>>(counts, S, bsum, n3);
    scanC<<<scanGrid, 256, 0, stream>>>(S, cursor, bsum, n3, 3 * E);
    csr_fill3<<<dim3(edgeGrid, 3), 256, 0, stream>>>(eA[0], eA[1], eA[2], cursor, srcs, E, N);

    // ---- layer 1 ----
    gemm128_rel<<<dim3(gemmGrid, 3), 256, 0, stream>>>(x, W1, T, N);
    csr_agg3<<<aggGrid, 256, 0, stream>>>(T, S, srcs, B1, N);
    gemm128<<<gemmGrid, 256, 0, stream>>>(B1, Wt1, lin1_b, B2, N, 1);   // h1 -> B2

    // ---- layer 2 ----
    gemm128_rel<<<dim3(gemmGrid, 3), 256, 0, stream>>>(B2, W2, T, N);
    csr_agg3<<<aggGrid, 256, 0, stream>>>(T, S, srcs, B1, N);
    gemm128<<<gemmGrid, 256, 0, stream>>>(B1, Wt2, lin2_b, B2, N, 1);   // h2 -> B2

    // ---- KAN linear + spline + fc (fused) ----
    gemm_kan<<<gemmGrid, 256, 0, stream>>>(B2, WtK, kan_b, alpha, beta, knots,
                                           spline_vals, M, fc_w, fc_b,
                                           (float*)d_out, N);
}

// Round 4
// 657.595 us; speedup vs baseline: 3.6748x; 1.2834x over previous
//
#include <hip/hip_runtime.h>

#define HD 128

typedef __attribute__((ext_vector_type(8))) short bf16x8;
typedef __attribute__((ext_vector_type(4))) float f32x4;
typedef __attribute__((ext_vector_type(4))) unsigned int u32x4;

static __device__ __forceinline__ float bf2f(unsigned short u) {
    union { unsigned int i; float f; } c; c.i = ((unsigned int)u) << 16; return c.f;
}
static __device__ __forceinline__ unsigned short f2bf(float f) {
    union { float f; unsigned int i; } c; c.f = f;
    unsigned int lsb = (c.i >> 16) & 1;
    c.i += 0x7fffu + lsb;
    return (unsigned short)(c.i >> 16);
}

// ---------------- spline second-derivative solve (natural cubic, K=5) ----------
__global__ void spline_solve(const float* __restrict__ knots,
                             const float* __restrict__ vals,
                             float* __restrict__ M) {
    int f = threadIdx.x;  // 128 features
    float kn[5], v[5];
#pragma unroll
    for (int i = 0; i < 5; ++i) { kn[i] = knots[i]; v[i] = vals[f * 5 + i]; }
    float h[4], sl[4];
#pragma unroll
    for (int i = 0; i < 4; ++i) { h[i] = kn[i + 1] - kn[i]; sl[i] = (v[i + 1] - v[i]) / h[i]; }
    float r0 = 6.f * (sl[1] - sl[0]);
    float r1 = 6.f * (sl[2] - sl[1]);
    float r2 = 6.f * (sl[3] - sl[2]);
    float d0 = 2.f * (h[0] + h[1]), d1 = 2.f * (h[1] + h[2]), d2 = 2.f * (h[2] + h[3]);
    float e0 = h[1], e1 = h[2];
    float w1 = e0 / d0;  float d1p = d1 - w1 * e0;  float r1p = r1 - w1 * r0;
    float w2 = e1 / d1p; float d2p = d2 - w2 * e1;  float r2p = r2 - w2 * r1p;
    float x2 = r2p / d2p;
    float x1 = (r1p - e1 * x2) / d1p;
    float x0 = (r0 - e0 * x1) / d0;
    M[f * 5 + 0] = 0.f; M[f * 5 + 1] = x0; M[f * 5 + 2] = x1; M[f * 5 + 3] = x2; M[f * 5 + 4] = 0.f;
}

// ---------------- weight prep: 9 mats -> bf16, col-major-by-output ------------
// Layout out[mat][c][k] such that B[k][c] = out[c][k] (k-contiguous per out col).
// mats 0..2: W1 rels (transpose), 3..5: W2 rels (transpose), 6: lin1, 7: lin2,
// 8: kan (these are already (out,in) row-major -> plain cast).
__global__ void wprep(const float* __restrict__ W1, const float* __restrict__ W2,
                      const float* __restrict__ l1, const float* __restrict__ l2,
                      const float* __restrict__ kw, unsigned short* __restrict__ Wt) {
    int mat = blockIdx.y, c = blockIdx.x, k = threadIdx.x;
    const float* src; int trans;
    if (mat < 3)      { src = W1 + (long)mat * 16384; trans = 1; }
    else if (mat < 6) { src = W2 + (long)(mat - 3) * 16384; trans = 1; }
    else if (mat == 6){ src = l1; trans = 0; }
    else if (mat == 7){ src = l2; trans = 0; }
    else              { src = kw; trans = 0; }
    float v = trans ? src[k * HD + c] : src[c * HD + k];
    Wt[(long)mat * 16384 + c * HD + k] = f2bf(v);
}

// ---------------- MFMA GEMM: C(n x 128) = A(n x 128, f32) @ W(128x128 bf16) ----
// MODE 0: out bf16 into T (n x 384), relation = blockIdx.y, no bias
// MODE 1: out f32 (n x 128), +bias, relu
// MODE 2: KAN: +bias(kan_b), affine(alpha,beta), cubic spline, dot fc_w -> out n x 1
template <int MODE>
__global__ __launch_bounds__(256) void mfma_gemm(
    const float* __restrict__ A, const unsigned short* __restrict__ Wt,
    void* __restrict__ Out, const float* __restrict__ bias,
    const float* __restrict__ alpha, const float* __restrict__ beta,
    const float* __restrict__ knots, const float* __restrict__ vals,
    const float* __restrict__ Msp, const float* __restrict__ fcw,
    const float* __restrict__ fcb, int n) {
    __shared__ unsigned short As[64 * HD];   // 16 KB, XOR-swizzled
    __shared__ unsigned short Ws[HD * HD];   // 32 KB, XOR-swizzled
    const int t = threadIdx.x;
    const int row0 = blockIdx.x * 64;
    const unsigned short* Wg = (MODE == 0) ? (Wt + (long)blockIdx.y * 16384) : Wt;

    // stage W: 2048 chunks of 16B; chunk i -> row c=i>>4, bytes i*16 within tile
    for (int i = t; i < 2048; i += 256) {
        u32x4 v = *(const u32x4*)(Wg + i * 8);
        int byte = (i * 16) ^ (((i >> 4) & 7) << 4);
        *(u32x4*)((char*)Ws + byte) = v;
    }
    // stage A (f32 -> bf16): 1024 chunks of 8 elems
    for (int i = t; i < 1024; i += 256) {
        int r = i >> 4;
        int k8 = (i & 15) << 3;
        int row = row0 + r;
        float4 f0 = make_float4(0.f, 0.f, 0.f, 0.f), f1 = f0;
        if (row < n) {
            f0 = *(const float4*)(A + (long)row * HD + k8);
            f1 = *(const float4*)(A + (long)row * HD + k8 + 4);
        }
        union { unsigned short us[8]; u32x4 v; } pk;
        pk.us[0] = f2bf(f0.x); pk.us[1] = f2bf(f0.y); pk.us[2] = f2bf(f0.z); pk.us[3] = f2bf(f0.w);
        pk.us[4] = f2bf(f1.x); pk.us[5] = f2bf(f1.y); pk.us[6] = f2bf(f1.z); pk.us[7] = f2bf(f1.w);
        int byte = (i * 16) ^ (((i >> 4) & 7) << 4);
        *(u32x4*)((char*)As + byte) = pk.v;
    }
    __syncthreads();

    const int w = t >> 6;        // wave -> rows [w*16, w*16+16)
    const int lane = t & 63;
    const int m = lane & 15;     // operand row/col index
    const int g = lane >> 4;     // k-group
    const int sw = (m & 7) << 4; // LDS swizzle for frag reads
    f32x4 acc[8];
#pragma unroll
    for (int ct = 0; ct < 8; ++ct) acc[ct] = (f32x4){0.f, 0.f, 0.f, 0.f};
#pragma unroll
    for (int ks = 0; ks < 4; ++ks) {
        const int kb = ks * 64 + g * 16;  // byte offset of this frag's k-slice
        bf16x8 af = *(const bf16x8*)((const char*)As + ((((w * 16 + m) << 8) + kb) ^ sw));
#pragma unroll
        for (int ct = 0; ct < 8; ++ct) {
            bf16x8 bf = *(const bf16x8*)((const char*)Ws + ((((ct * 16 + m) << 8) + kb) ^ sw));
            acc[ct] = __builtin_amdgcn_mfma_f32_16x16x32_bf16(af, bf, acc[ct], 0, 0, 0);
        }
    }

    if (MODE == 0) {
        unsigned short* T = (unsigned short*)Out;
        const long cbase = (long)blockIdx.y * HD;
#pragma unroll
        for (int ct = 0; ct < 8; ++ct) {
#pragma unroll
            for (int r = 0; r < 4; ++r) {
                int row = row0 + w * 16 + g * 4 + r;
                if (row < n) T[(long)row * 384 + cbase + ct * 16 + m] = f2bf(acc[ct][r]);
            }
        }
    } else if (MODE == 1) {
        float* C = (float*)Out;
#pragma unroll
        for (int ct = 0; ct < 8; ++ct) {
            float bv = bias[ct * 16 + m];
#pragma unroll
            for (int r = 0; r < 4; ++r) {
                int row = row0 + w * 16 + g * 4 + r;
                if (row < n) C[(long)row * HD + ct * 16 + m] = fmaxf(acc[ct][r] + bv, 0.f);
            }
        }
    } else {
        float kn[5];
#pragma unroll
        for (int i = 0; i < 5; ++i) kn[i] = knots[i];
        float part[4] = {0.f, 0.f, 0.f, 0.f};
#pragma unroll
        for (int ct = 0; ct < 8; ++ct) {
            int f = ct * 16 + m;
            float kb = bias[f], al = alpha[f], be = beta[f], fw = fcw[f];
#pragma unroll
            for (int r = 0; r < 4; ++r) {
                float xv = al * (acc[ct][r] + kb) + be;
                int j = -1;
#pragma unroll
                for (int k = 0; k < 5; ++k) j += (xv >= kn[k]) ? 1 : 0;
                j = max(0, min(3, j));
                float t0 = kn[j], t1 = kn[j + 1];
                float hj = t1 - t0;
                float y0 = vals[f * 5 + j], y1 = vals[f * 5 + j + 1];
                float M0 = Msp[f * 5 + j], M1 = Msp[f * 5 + j + 1];
                float a = t1 - xv, b = xv - t0;
                float inv6h = 1.f / (6.f * hj);
                float s = M0 * a * a * a * inv6h + M1 * b * b * b * inv6h
                        + (y0 / hj - M0 * hj / 6.f) * a + (y1 / hj - M1 * hj / 6.f) * b;
                part[r] += s * fw;
            }
        }
#pragma unroll
        for (int o = 1; o < 16; o <<= 1) {
#pragma unroll
            for (int r = 0; r < 4; ++r) part[r] += __shfl_xor(part[r], o);
        }
        if (m == 0) {
#pragma unroll
            for (int r = 0; r < 4; ++r) {
                int row = row0 + w * 16 + g * 4 + r;
                if (row < n) ((float*)Out)[row] = part[r] + fcb[0];
            }
        }
    }
}

// ---------------- CSR build (fused over 3 relations, blockIdx.y = relation) ----
__global__ void csr_count3(const int* __restrict__ e0, const int* __restrict__ e1,
                           const int* __restrict__ e2, int* __restrict__ counts,
                           int E, int N) {
    int r = blockIdx.y;
    const int* dst = (r == 0) ? e0 : ((r == 1) ? e1 : e2);
    int e = blockIdx.x * blockDim.x + threadIdx.x;
    if (e < E) atomicAdd(&counts[(long)r * N + dst[e]], 1);
}

__global__ __launch_bounds__(256) void scanA(const int* __restrict__ cnt,
                                             int* __restrict__ S,
                                             int* __restrict__ bsum, int n) {
    __shared__ int ts[256];
    const int t = threadIdx.x;
    const int base = blockIdx.x * 2048 + t * 8;
    int v[8];
    int s = 0;
#pragma unroll
    for (int i = 0; i < 8; ++i) {
        int j = base + i;
        v[i] = (j < n) ? cnt[j] : 0;
        s += v[i];
    }
    ts[t] = s;
    __syncthreads();
    for (int off = 1; off < 256; off <<= 1) {
        int x = (t >= off) ? ts[t - off] : 0;
        __syncthreads();
        ts[t] += x;
        __syncthreads();
    }
    int excl = ts[t] - s;
#pragma unroll
    for (int i = 0; i < 8; ++i) {
        int j = base + i;
        if (j < n) S[j] = excl;
        excl += v[i];
    }
    if (t == 255) bsum[blockIdx.x] = ts[255];
}

__global__ __launch_bounds__(256) void scanC(int* __restrict__ S,
                                             int* __restrict__ cursor,
                                             const int* __restrict__ bsum,
                                             int n, int total) {
    __shared__ int red[256];
    const int t = threadIdx.x;
    int acc = 0;
    for (int b = t; b < blockIdx.x; b += 256) acc += bsum[b];
    red[t] = acc;
    __syncthreads();
    for (int o = 128; o; o >>= 1) {
        if (t < o) red[t] += red[t + o];
        __syncthreads();
    }
    const int off = red[0];
    const int base = blockIdx.x * 2048 + t * 8;
#pragma unroll
    for (int i = 0; i < 8; ++i) {
        int j = base + i;
        if (j < n) {
            int val = S[j] + off;
            S[j] = val;
            cursor[j] = val;
        }
    }
    if (blockIdx.x == gridDim.x - 1 && t == 0) S[n] = total;
}

__global__ void csr_fill3(const int* __restrict__ e0, const int* __restrict__ e1,
                          const int* __restrict__ e2, int* __restrict__ cursor,
                          unsigned short* __restrict__ srcs, int E, int N) {
    int r = blockIdx.y;
    const int* eb = (r == 0) ? e0 : ((r == 1) ? e1 : e2);
    int e = blockIdx.x * blockDim.x + threadIdx.x;
    if (e < E) {
        int pos = atomicAdd(&cursor[(long)r * N + eb[e]], 1);
        srcs[pos] = (unsigned short)eb[E + e];
    }
}

// ---------------- fused 3-relation gather aggregation (bf16 in, f32 out) -------
__global__ __launch_bounds__(256) void csr_agg3(const unsigned short* __restrict__ T,
                                                const int* __restrict__ S,
                                                const unsigned short* __restrict__ srcs,
                                                float* __restrict__ out, int N) {
    const int g = threadIdx.x >> 5;
    const int lane = threadIdx.x & 31;
    const int d = blockIdx.x * 8 + g;
    if (d >= N) return;
    float a0[4] = {0.f, 0.f, 0.f, 0.f};
    float a1[4] = {0.f, 0.f, 0.f, 0.f};
    float a2[4] = {0.f, 0.f, 0.f, 0.f};
    float a3[4] = {0.f, 0.f, 0.f, 0.f};
#pragma unroll
    for (int r = 0; r < 3; ++r) {
        const int beg = S[(long)r * N + d];
        const int end = S[(long)r * N + d + 1];
        const unsigned short* Tb = T + r * HD + lane * 4;
        int e = beg;
        for (; e + 3 < end; e += 4) {
            int s0 = srcs[e], s1 = srcs[e + 1], s2 = srcs[e + 2], s3 = srcs[e + 3];
            ushort4 u0 = *(const ushort4*)&Tb[(long)s0 * 384];
            ushort4 u1 = *(const ushort4*)&Tb[(long)s1 * 384];
            ushort4 u2 = *(const ushort4*)&Tb[(long)s2 * 384];
            ushort4 u3 = *(const ushort4*)&Tb[(long)s3 * 384];
            a0[0] += bf2f(u0.x); a0[1] += bf2f(u0.y); a0[2] += bf2f(u0.z); a0[3] += bf2f(u0.w);
            a1[0] += bf2f(u1.x); a1[1] += bf2f(u1.y); a1[2] += bf2f(u1.z); a1[3] += bf2f(u1.w);
            a2[0] += bf2f(u2.x); a2[1] += bf2f(u2.y); a2[2] += bf2f(u2.z); a2[3] += bf2f(u2.w);
            a3[0] += bf2f(u3.x); a3[1] += bf2f(u3.y); a3[2] += bf2f(u3.z); a3[3] += bf2f(u3.w);
        }
        for (; e < end; ++e) {
            ushort4 u0 = *(const ushort4*)&Tb[(long)srcs[e] * 384];
            a0[0] += bf2f(u0.x); a0[1] += bf2f(u0.y); a0[2] += bf2f(u0.z); a0[3] += bf2f(u0.w);
        }
    }
    float4 o;
    o.x = (a0[0] + a1[0]) + (a2[0] + a3[0]);
    o.y = (a0[1] + a1[1]) + (a2[1] + a3[1]);
    o.z = (a0[2] + a1[2]) + (a2[2] + a3[2]);
    o.w = (a0[3] + a1[3]) + (a2[3] + a3[3]);
    *(float4*)&out[(long)d * HD + lane * 4] = o;
}

extern "C" void kernel_launch(void* const* d_in, const int* in_sizes, int n_in,
                              void* d_out, int out_size, void* d_ws, size_t ws_size,
                              hipStream_t stream) {
    const float* x       = (const float*)d_in[0];
    const int*   eA[3]   = {(const int*)d_in[1], (const int*)d_in[2], (const int*)d_in[3]};
    const float* W1      = (const float*)d_in[4];
    const float* lin1_w  = (const float*)d_in[5];
    const float* lin1_b  = (const float*)d_in[6];
    const float* W2      = (const float*)d_in[7];
    const float* lin2_w  = (const float*)d_in[8];
    const float* lin2_b  = (const float*)d_in[9];
    const float* kan_w   = (const float*)d_in[10];
    const float* kan_b   = (const float*)d_in[11];
    const float* alpha   = (const float*)d_in[12];
    const float* beta    = (const float*)d_in[13];
    const float* knots   = (const float*)d_in[14];
    const float* spline_vals = (const float*)d_in[15];
    const float* fc_w    = (const float*)d_in[16];
    const float* fc_b    = (const float*)d_in[17];

    const int N = in_sizes[0] / HD;
    const int E = in_sizes[1] / 2;
    const int n3 = 3 * N;

    // ---- workspace carve (bytes, keep 256B alignment) ----
    char* p = (char*)d_ws;
    float* M      = (float*)p;              p += 4096;
    unsigned short* Wt = (unsigned short*)p; p += (size_t)9 * 16384 * 2;   // 288 KB
    int*   counts = (int*)p;                p += (size_t)n3 * 4 + 256;
    int*   S      = (int*)p;                p += (size_t)(n3 + 1) * 4 + 256;
    int*   cursor = (int*)p;                p += (size_t)n3 * 4 + 256;
    int*   bsum   = (int*)p;                p += 4096;
    unsigned short* srcs = (unsigned short*)p; p += (size_t)3 * E * 2 + 256;
    unsigned short* T = (unsigned short*)p; p += (size_t)N * 384 * 2;
    float* B1     = (float*)p;              p += (size_t)N * HD * 4;  // agg out
    float* B2     = (float*)p;              p += (size_t)N * HD * 4;  // h1 / h2

    const int g64     = (N + 63) / 64;
    const int aggGrid = (N + 7) / 8;
    const int edgeGrid = (E + 255) / 256;
    const int scanGrid = (n3 + 2047) / 2048;

    // small precomputes
    spline_solve<<<1, 128, 0, stream>>>(knots, spline_vals, M);
    wprep<<<dim3(128, 9), 128, 0, stream>>>(W1, W2, lin1_w, lin2_w, kan_w, Wt);

    // ---- CSR build (once; reused by both layers) ----
    hipMemsetAsync(counts, 0, (size_t)n3 * 4, stream);
    csr_count3<<<dim3(edgeGrid, 3), 256, 0, stream>>>(eA[0], eA[1], eA[2], counts, E, N);
    scanA<<<scanGrid, 256, 0, stream>>>(counts, S, bsum, n3);
    scanC<<<scanGrid, 256, 0, stream>>>(S, cursor, bsum, n3, 3 * E);
    csr_fill3<<<dim3(edgeGrid, 3), 256, 0, stream>>>(eA[0], eA[1], eA[2], cursor, srcs, E, N);

    // ---- layer 1 ----
    mfma_gemm<0><<<dim3(g64, 3), 256, 0, stream>>>(x, Wt, T, nullptr, nullptr, nullptr,
                                                   nullptr, nullptr, nullptr, nullptr, nullptr, N);
    csr_agg3<<<aggGrid, 256, 0, stream>>>(T, S, srcs, B1, N);
    mfma_gemm<1><<<g64, 256, 0, stream>>>(B1, Wt + (size_t)6 * 16384, B2, lin1_b, nullptr,
                                          nullptr, nullptr, nullptr, nullptr, nullptr, nullptr, N);

    // ---- layer 2 ----
    mfma_gemm<0><<<dim3(g64, 3), 256, 0, stream>>>(B2, Wt + (size_t)3 * 16384, T, nullptr, nullptr,
                                                   nullptr, nullptr, nullptr, nullptr, nullptr, nullptr, N);
    csr_agg3<<<aggGrid, 256, 0, stream>>>(T, S, srcs, B1, N);
    mfma_gemm<1><<<g64, 256, 0, stream>>>(B1, Wt + (size_t)7 * 16384, B2, lin2_b, nullptr,
                                          nullptr, nullptr, nullptr, nullptr, nullptr, nullptr, N);

    // ---- KAN linear + spline + fc (fused, MFMA) ----
    mfma_gemm<2><<<g64, 256, 0, stream>>>(B2, Wt + (size_t)8 * 16384, d_out, kan_b, alpha,
                                          beta, knots, spline_vals, M, fc_w, fc_b, N);
}